// Round 5
// baseline (404.311 us; speedup 1.0000x reference)
//
#include <hip/hip_runtime.h>
#include <cstddef>

#define GAT_N 50000
#define GAT_E 300000
#define SCAN_B 256

typedef short bf16x8 __attribute__((ext_vector_type(8)));
typedef float f32x4  __attribute__((ext_vector_type(4)));

__device__ __forceinline__ ushort f2bf(float f) {
    unsigned u = __float_as_uint(f);
    return (ushort)((u + 0x7fffu + ((u >> 16) & 1u)) >> 16);
}
__device__ __forceinline__ float bf2f(ushort h) {
    return __uint_as_float((unsigned)h << 16);
}

// ---------------- CSR build ----------------

__global__ __launch_bounds__(256) void zero_ints(int* __restrict__ a, int n) {
    int i = blockIdx.x * blockDim.x + threadIdx.x;
    int stride = gridDim.x * blockDim.x;
    for (; i < n; i += stride) a[i] = 0;
}

__global__ __launch_bounds__(256) void count_k(
    const int* __restrict__ dst, int* __restrict__ cnt, int E)
{
    int e = blockIdx.x * blockDim.x + threadIdx.x;
    if (e < E) atomicAdd(&cnt[dst[e]], 1);
}

__global__ __launch_bounds__(256) void csr_partial(
    const int* __restrict__ cnt, int* __restrict__ partials, int N, int chunk)
{
    __shared__ int red[256];
    int b = blockIdx.x, t = threadIdx.x;
    int s = 0;
    for (int i = t; i < chunk; i += 256) {
        int idx = b * chunk + i;
        if (idx < N) s += cnt[idx];
    }
    red[t] = s;
    __syncthreads();
    for (int off = 128; off > 0; off >>= 1) {
        if (t < off) red[t] += red[t + off];
        __syncthreads();
    }
    if (t == 0) partials[b] = red[0];
}

__global__ __launch_bounds__(SCAN_B) void csr_scanp(
    int* __restrict__ partials, int* __restrict__ rowptr, int N)
{
    __shared__ int sc[SCAN_B];
    int t = threadIdx.x;
    int v = partials[t];
    sc[t] = v;
    __syncthreads();
    for (int off = 1; off < SCAN_B; off <<= 1) {
        int u = (t >= off) ? sc[t - off] : 0;
        __syncthreads();
        sc[t] += u;
        __syncthreads();
    }
    partials[t] = sc[t] - v;
    if (t == SCAN_B - 1) rowptr[N] = sc[t];
}

__global__ __launch_bounds__(256) void csr_write(
    const int* __restrict__ cnt, const int* __restrict__ partials,
    int* __restrict__ rowptr, int N, int chunk)
{
    __shared__ int sc[256];
    int b = blockIdx.x, t = threadIdx.x;
    int idx = b * chunk + t;
    int v = (t < chunk && idx < N) ? cnt[idx] : 0;
    sc[t] = v;
    __syncthreads();
    for (int off = 1; off < 256; off <<= 1) {
        int u = (t >= off) ? sc[t - off] : 0;
        __syncthreads();
        sc[t] += u;
        __syncthreads();
    }
    if (t < chunk && idx < N) rowptr[idx] = partials[b] + sc[t] - v;
}

__global__ __launch_bounds__(256) void scatter_k(
    const int* __restrict__ src, const int* __restrict__ dst,
    const int* __restrict__ rowptr, int* __restrict__ cursor,
    int* __restrict__ ssrc, int* __restrict__ sdst, int E)
{
    int e = blockIdx.x * blockDim.x + threadIdx.x;
    if (e >= E) return;
    int d = dst[e];
    int p = rowptr[d] + atomicAdd(&cursor[d], 1);
    ssrc[p] = src[e];
    sdst[p] = d;
}

// ---------------- precision-split converts ----------------

__global__ __launch_bounds__(256) void convert_x(
    const float* __restrict__ x, ushort* __restrict__ Xh, ushort* __restrict__ Xl,
    long total4)
{
    long i = (long)blockIdx.x * blockDim.x + threadIdx.x;
    long stride = (long)gridDim.x * blockDim.x;
    for (; i < total4; i += stride) {
        float4 v = *(const float4*)(x + i * 4);
        ushort4 h, lo;
        h.x = f2bf(v.x); lo.x = f2bf(v.x - bf2f(h.x));
        h.y = f2bf(v.y); lo.y = f2bf(v.y - bf2f(h.y));
        h.z = f2bf(v.z); lo.z = f2bf(v.z - bf2f(h.z));
        h.w = f2bf(v.w); lo.w = f2bf(v.w - bf2f(h.w));
        *(ushort4*)(Xh + i * 4) = h;
        *(ushort4*)(Xl + i * 4) = lo;
    }
}

__global__ __launch_bounds__(256) void convert_w(
    const float* __restrict__ W, ushort* __restrict__ Wth, ushort* __restrict__ Wtl,
    int K, int M, int Mp)
{
    int idx = blockIdx.x * blockDim.x + threadIdx.x;
    if (idx >= Mp * K) return;
    int c = idx / K, k = idx - c * K;
    float v = (c < M) ? W[(size_t)k * M + c] : 0.f;
    ushort h = f2bf(v);
    Wth[idx] = h;
    Wtl[idx] = f2bf(v - bf2f(h));
}

// ---------------- bf16x3 MFMA GEMM + score epilogue ----------------

#define LDK 40

__global__ __launch_bounds__(256) void gemm_feat(
    const ushort* __restrict__ Ah, const ushort* __restrict__ Al,
    const ushort* __restrict__ Wh, const ushort* __restrict__ Wl,
    const float* __restrict__ alw, const float* __restrict__ arw,
    float* __restrict__ feat, float* __restrict__ el, float* __restrict__ er,
    int N, int K, int M, int H, int D, int ldF)
{
    __shared__ ushort As_h[128 * LDK];
    __shared__ ushort As_l[128 * LDK];
    __shared__ ushort Bs_h[128 * LDK];
    __shared__ ushort Bs_l[128 * LDK];

    const int m0 = blockIdx.x * 128;
    const int n0 = blockIdx.y * 128;
    const int t = threadIdx.x;
    const int w = t >> 6, lane = t & 63;
    const int lr = lane & 15, lg = lane >> 4;
    const int wr = (w >> 1) * 64, wc = (w & 1) * 64;

    f32x4 acc[4][4] = {};

    for (int k0 = 0; k0 < K; k0 += 32) {
        #pragma unroll
        for (int l = 0; l < 2; ++l) {
            int idx = t + l * 256;
            int row = idx >> 2, kk = (idx & 3) * 8;
            bf16x8 vh = {}, vl = {};
            int gr = m0 + row;
            if (gr < N) {
                vh = *(const bf16x8*)(Ah + (size_t)gr * K + k0 + kk);
                vl = *(const bf16x8*)(Al + (size_t)gr * K + k0 + kk);
            }
            bf16x8 wh = *(const bf16x8*)(Wh + (size_t)(n0 + row) * K + k0 + kk);
            bf16x8 wl = *(const bf16x8*)(Wl + (size_t)(n0 + row) * K + k0 + kk);
            *(bf16x8*)&As_h[row * LDK + kk] = vh;
            *(bf16x8*)&As_l[row * LDK + kk] = vl;
            *(bf16x8*)&Bs_h[row * LDK + kk] = wh;
            *(bf16x8*)&Bs_l[row * LDK + kk] = wl;
        }
        __syncthreads();

        bf16x8 a_h[4], a_l[4];
        #pragma unroll
        for (int fi = 0; fi < 4; ++fi) {
            a_h[fi] = *(const bf16x8*)&As_h[(wr + fi * 16 + lr) * LDK + lg * 8];
            a_l[fi] = *(const bf16x8*)&As_l[(wr + fi * 16 + lr) * LDK + lg * 8];
        }
        #pragma unroll
        for (int fj = 0; fj < 4; ++fj) {
            bf16x8 b_h = *(const bf16x8*)&Bs_h[(wc + fj * 16 + lr) * LDK + lg * 8];
            bf16x8 b_l = *(const bf16x8*)&Bs_l[(wc + fj * 16 + lr) * LDK + lg * 8];
            #pragma unroll
            for (int fi = 0; fi < 4; ++fi) {
                acc[fi][fj] = __builtin_amdgcn_mfma_f32_16x16x32_bf16(a_h[fi], b_h, acc[fi][fj], 0, 0, 0);
                acc[fi][fj] = __builtin_amdgcn_mfma_f32_16x16x32_bf16(a_l[fi], b_h, acc[fi][fj], 0, 0, 0);
                acc[fi][fj] = __builtin_amdgcn_mfma_f32_16x16x32_bf16(a_h[fi], b_l, acc[fi][fj], 0, 0, 0);
            }
        }
        __syncthreads();
    }

    #pragma unroll
    for (int fi = 0; fi < 4; ++fi) {
        #pragma unroll
        for (int q = 0; q < 4; ++q) {
            int row = m0 + wr + fi * 16 + 4 * lg + q;
            if (row < N) {
                #pragma unroll
                for (int fj = 0; fj < 4; ++fj) {
                    int col = n0 + wc + fj * 16 + lr;
                    if (col < M) feat[(size_t)row * ldF + col] = acc[fi][fj][q];
                }
            }
        }
    }

    const int head = (n0 + wc) / D;
    if (head < H) {
        float alv[4], arv[4];
        #pragma unroll
        for (int fj = 0; fj < 4; ++fj) {
            int col = n0 + wc + fj * 16 + lr;
            alv[fj] = (col < M) ? alw[col] : 0.f;
            arv[fj] = (col < M) ? arw[col] : 0.f;
        }
        #pragma unroll
        for (int fi = 0; fi < 4; ++fi) {
            #pragma unroll
            for (int q = 0; q < 4; ++q) {
                float s1 = 0.f, s2 = 0.f;
                #pragma unroll
                for (int fj = 0; fj < 4; ++fj) {
                    s1 = fmaf(acc[fi][fj][q], alv[fj], s1);
                    s2 = fmaf(acc[fi][fj][q], arv[fj], s2);
                }
                #pragma unroll
                for (int mask = 1; mask <= 8; mask <<= 1) {
                    s1 += __shfl_xor(s1, mask);
                    s2 += __shfl_xor(s2, mask);
                }
                int row = m0 + wr + fi * 16 + 4 * lg + q;
                if (lr == 0 && row < N) {
                    el[(size_t)row * H + head] = s1;
                    er[(size_t)row * H + head] = s2;
                }
            }
        }
    }
}

// ---------------- edge scores in CSR order ----------------

// H=4: sc[p*4+h] = leaky(el[src*4+h] + er[dst*4+h])
__global__ __launch_bounds__(256) void edge_score4(
    const int* __restrict__ ssrc, const int* __restrict__ sdst,
    const float* __restrict__ el, const float* __restrict__ er,
    float* __restrict__ sc, int E)
{
    int p = blockIdx.x * blockDim.x + threadIdx.x;
    if (p >= E) return;
    int s = ssrc[p], d = sdst[p];
    float4 a = *(const float4*)(el + (size_t)s * 4);
    float4 b = *(const float4*)(er + (size_t)d * 4);
    float4 v;
    v.x = a.x + b.x; v.x = v.x > 0.f ? v.x : 0.2f * v.x;
    v.y = a.y + b.y; v.y = v.y > 0.f ? v.y : 0.2f * v.y;
    v.z = a.z + b.z; v.z = v.z > 0.f ? v.z : 0.2f * v.z;
    v.w = a.w + b.w; v.w = v.w > 0.f ? v.w : 0.2f * v.w;
    *(float4*)(sc + (size_t)p * 4) = v;
}

__global__ __launch_bounds__(256) void edge_score1(
    const int* __restrict__ ssrc, const int* __restrict__ sdst,
    const float* __restrict__ el, const float* __restrict__ er,
    float* __restrict__ sc, int E)
{
    int p = blockIdx.x * blockDim.x + threadIdx.x;
    if (p >= E) return;
    float v = el[ssrc[p]] + er[sdst[p]];
    sc[p] = v > 0.f ? v : 0.2f * v;
}

// ---------------- fused softmax aggregation ----------------

// wave per (node, 128-channel half); float2/lane; h = 2*half + (lane>>5)
__global__ __launch_bounds__(256) void node_aggr256(
    const int* __restrict__ rowptr, const int* __restrict__ ssrc,
    const float* __restrict__ sc, const float* __restrict__ feat,
    const float* __restrict__ bias,
    ushort* __restrict__ Ah_out, ushort* __restrict__ Al_out, int N)
{
    int wid = blockIdx.x * 4 + (threadIdx.x >> 6);
    int n = wid >> 1;
    if (n >= N) return;
    int half = wid & 1;
    int lane = threadIdx.x & 63;
    int c = half * 128 + lane * 2;
    int h = c >> 6;
    int beg = rowptr[n], end = rowptr[n + 1];

    float m = -__builtin_inff();
    for (int j = beg; j < end; ++j)
        m = fmaxf(m, sc[(size_t)j * 4 + h]);

    float denom = 0.f;
    float a0 = 0.f, a1 = 0.f;
    for (int j = beg; j < end; ++j) {
        float wgt = __expf(sc[(size_t)j * 4 + h] - m);
        denom += wgt;
        int s = ssrc[j];
        float2 f = *(const float2*)(feat + (size_t)s * 256 + c);
        a0 = fmaf(wgt, f.x, a0);
        a1 = fmaf(wgt, f.y, a1);
    }
    float inv = 1.f / fmaxf(denom, 1e-9f);
    float v0 = fmaf(a0, inv, bias[c + 0]);
    float v1 = fmaf(a1, inv, bias[c + 1]);
    ushort2 hh, lo;
    hh.x = f2bf(v0); lo.x = f2bf(v0 - bf2f(hh.x));
    hh.y = f2bf(v1); lo.y = f2bf(v1 - bf2f(hh.y));
    *(ushort2*)(Ah_out + (size_t)n * 256 + c) = hh;
    *(ushort2*)(Al_out + (size_t)n * 256 + c) = lo;
}

// wave per node; H=1, D=47, feat stride 48
__global__ __launch_bounds__(256) void node_aggr47(
    const int* __restrict__ rowptr, const int* __restrict__ ssrc,
    const float* __restrict__ sc, const float* __restrict__ feat,
    const float* __restrict__ bias, float* __restrict__ out, int N)
{
    int n = blockIdx.x * 4 + (threadIdx.x >> 6);
    if (n >= N) return;
    int lane = threadIdx.x & 63;
    int beg = rowptr[n], end = rowptr[n + 1];

    float m = -__builtin_inff();
    for (int j = beg; j < end; ++j)
        m = fmaxf(m, sc[j]);

    float denom = 0.f, acc = 0.f;
    for (int j = beg; j < end; ++j) {
        float wgt = __expf(sc[j] - m);
        denom += wgt;
        int s = ssrc[j];
        float f = (lane < 47) ? feat[(size_t)s * 48 + lane] : 0.f;
        acc = fmaf(wgt, f, acc);
    }
    float inv = 1.f / fmaxf(denom, 1e-9f);
    if (lane < 47)
        out[(size_t)n * 47 + lane] = fmaf(acc, inv, bias[lane]);
}

// ---------------- launch ----------------

extern "C" void kernel_launch(void* const* d_in, const int* in_sizes, int n_in,
                              void* d_out, int out_size, void* d_ws, size_t ws_size,
                              hipStream_t stream) {
    const float* x   = (const float*)d_in[0];
    const int*   src = (const int*)d_in[1];
    const int*   dst = (const int*)d_in[2];
    const float* W1  = (const float*)d_in[3];
    const float* al1 = (const float*)d_in[4];
    const float* ar1 = (const float*)d_in[5];
    const float* b1  = (const float*)d_in[6];
    const float* W2  = (const float*)d_in[7];
    const float* al2 = (const float*)d_in[8];
    const float* ar2 = (const float*)d_in[9];
    const float* b2  = (const float*)d_in[10];
    const float* W3  = (const float*)d_in[11];
    const float* al3 = (const float*)d_in[12];
    const float* ar3 = (const float*)d_in[13];
    const float* b3  = (const float*)d_in[14];
    float* out = (float*)d_out;

    const int N = GAT_N, E = GAT_E;
    const int chunk = (N + SCAN_B - 1) / SCAN_B;

    char* wsb = (char*)d_ws;
    size_t o = 0;
    float*  feat  = (float*)(wsb + o);  o += (size_t)N * 256 * 4;
    ushort* Ah    = (ushort*)(wsb + o); o += (size_t)N * 256 * 2;
    ushort* Al    = (ushort*)(wsb + o); o += (size_t)N * 256 * 2;
    float*  el    = (float*)(wsb + o);  o += (size_t)N * 4 * 4;
    float*  er    = (float*)(wsb + o);  o += (size_t)N * 4 * 4;
    int* rowptr   = (int*)(wsb + o);    o += (size_t)(N + 1) * 4;
    int* cnt      = (int*)(wsb + o);    o += (size_t)N * 4;
    int* cursor   = (int*)(wsb + o);    o += (size_t)N * 4;
    int* ssrc     = (int*)(wsb + o);    o += (size_t)E * 4;
    int* sdst     = (int*)(wsb + o);    o += (size_t)E * 4;
    float* scbuf  = (float*)(wsb + o);  o += (size_t)E * 4 * 4;
    int* partials = (int*)(wsb + o);    o += (size_t)SCAN_B * 4;
    ushort* Wt1h  = (ushort*)(wsb + o); o += (size_t)256 * 128 * 2;
    ushort* Wt1l  = (ushort*)(wsb + o); o += (size_t)256 * 128 * 2;
    ushort* Wt2h  = (ushort*)(wsb + o); o += (size_t)256 * 256 * 2;
    ushort* Wt2l  = (ushort*)(wsb + o); o += (size_t)256 * 256 * 2;
    ushort* Wt3h  = (ushort*)(wsb + o); o += (size_t)128 * 256 * 2;
    ushort* Wt3l  = (ushort*)(wsb + o); o += (size_t)128 * 256 * 2;
    ushort* Xh = Ah;
    ushort* Xl = Al;

    dim3 blk(256);
    int gE = (E + 255) / 256;
    int gN = (N + 3) / 4;
    int gN2 = (2 * N + 3) / 4;
    dim3 gemmG((N + 127) / 128, 2);
    dim3 gemmG3((N + 127) / 128, 1);

    // ---- CSR build
    zero_ints<<<64, blk, 0, stream>>>(cnt, 2 * N);
    count_k<<<gE, blk, 0, stream>>>(dst, cnt, E);
    csr_partial<<<SCAN_B, blk, 0, stream>>>(cnt, partials, N, chunk);
    csr_scanp<<<1, SCAN_B, 0, stream>>>(partials, rowptr, N);
    csr_write<<<SCAN_B, blk, 0, stream>>>(cnt, partials, rowptr, N, chunk);
    scatter_k<<<gE, blk, 0, stream>>>(src, dst, rowptr, cursor, ssrc, sdst, E);

    // ---- converts
    convert_x<<<2048, blk, 0, stream>>>(x, Xh, Xl, (long)N * 128 / 4);
    convert_w<<<(256 * 128 + 255) / 256, blk, 0, stream>>>(W1, Wt1h, Wt1l, 128, 256, 256);
    convert_w<<<(256 * 256 + 255) / 256, blk, 0, stream>>>(W2, Wt2h, Wt2l, 256, 256, 256);
    convert_w<<<(128 * 256 + 255) / 256, blk, 0, stream>>>(W3, Wt3h, Wt3l, 256, 47, 128);

    // ---- layer 1
    gemm_feat<<<gemmG, blk, 0, stream>>>(Xh, Xl, Wt1h, Wt1l, al1, ar1,
                                         feat, el, er, N, 128, 256, 4, 64, 256);
    edge_score4<<<gE, blk, 0, stream>>>(ssrc, sdst, el, er, scbuf, E);
    node_aggr256<<<gN2, blk, 0, stream>>>(rowptr, ssrc, scbuf, feat, b1, Ah, Al, N);

    // ---- layer 2
    gemm_feat<<<gemmG, blk, 0, stream>>>(Ah, Al, Wt2h, Wt2l, al2, ar2,
                                         feat, el, er, N, 256, 256, 4, 64, 256);
    edge_score4<<<gE, blk, 0, stream>>>(ssrc, sdst, el, er, scbuf, E);
    node_aggr256<<<gN2, blk, 0, stream>>>(rowptr, ssrc, scbuf, feat, b2, Ah, Al, N);

    // ---- layer 3 (feat stride 48)
    gemm_feat<<<gemmG3, blk, 0, stream>>>(Ah, Al, Wt3h, Wt3l, al3, ar3,
                                          feat, el, er, N, 256, 47, 1, 47, 48);
    edge_score1<<<gE, blk, 0, stream>>>(ssrc, sdst, el, er, scbuf, E);
    node_aggr47<<<gN, blk, 0, stream>>>(rowptr, ssrc, scbuf, feat, b3, out, N);
}

// Round 6
// 332.235 us; speedup vs baseline: 1.2169x; 1.2169x over previous
//
#include <hip/hip_runtime.h>
#include <cstddef>

#define GAT_N 50000
#define GAT_E 300000
#define SCAN_B 256

typedef short bf16x8 __attribute__((ext_vector_type(8)));
typedef float f32x4  __attribute__((ext_vector_type(4)));

__device__ __forceinline__ ushort f2bf(float f) {
    unsigned u = __float_as_uint(f);
    return (ushort)((u + 0x7fffu + ((u >> 16) & 1u)) >> 16);
}
__device__ __forceinline__ float bf2f(ushort h) {
    return __uint_as_float((unsigned)h << 16);
}

// ---------------- CSR build ----------------

__global__ __launch_bounds__(256) void zero_ints(int* __restrict__ a, int n) {
    int i = blockIdx.x * blockDim.x + threadIdx.x;
    int stride = gridDim.x * blockDim.x;
    for (; i < n; i += stride) a[i] = 0;
}

__global__ __launch_bounds__(256) void count_k(
    const int* __restrict__ dst, int* __restrict__ cnt, int E)
{
    int e = blockIdx.x * blockDim.x + threadIdx.x;
    if (e < E) atomicAdd(&cnt[dst[e]], 1);
}

__global__ __launch_bounds__(256) void csr_partial(
    const int* __restrict__ cnt, int* __restrict__ partials, int N, int chunk)
{
    __shared__ int red[256];
    int b = blockIdx.x, t = threadIdx.x;
    int s = 0;
    for (int i = t; i < chunk; i += 256) {
        int idx = b * chunk + i;
        if (idx < N) s += cnt[idx];
    }
    red[t] = s;
    __syncthreads();
    for (int off = 128; off > 0; off >>= 1) {
        if (t < off) red[t] += red[t + off];
        __syncthreads();
    }
    if (t == 0) partials[b] = red[0];
}

__global__ __launch_bounds__(SCAN_B) void csr_scanp(
    int* __restrict__ partials, int* __restrict__ rowptr, int N)
{
    __shared__ int sc[SCAN_B];
    int t = threadIdx.x;
    int v = partials[t];
    sc[t] = v;
    __syncthreads();
    for (int off = 1; off < SCAN_B; off <<= 1) {
        int u = (t >= off) ? sc[t - off] : 0;
        __syncthreads();
        sc[t] += u;
        __syncthreads();
    }
    partials[t] = sc[t] - v;
    if (t == SCAN_B - 1) rowptr[N] = sc[t];
}

__global__ __launch_bounds__(256) void csr_write(
    const int* __restrict__ cnt, const int* __restrict__ partials,
    int* __restrict__ rowptr, int N, int chunk)
{
    __shared__ int sc[256];
    int b = blockIdx.x, t = threadIdx.x;
    int idx = b * chunk + t;
    int v = (t < chunk && idx < N) ? cnt[idx] : 0;
    sc[t] = v;
    __syncthreads();
    for (int off = 1; off < 256; off <<= 1) {
        int u = (t >= off) ? sc[t - off] : 0;
        __syncthreads();
        sc[t] += u;
        __syncthreads();
    }
    if (t < chunk && idx < N) rowptr[idx] = partials[b] + sc[t] - v;
}

__global__ __launch_bounds__(256) void scatter_k(
    const int* __restrict__ src, const int* __restrict__ dst,
    const int* __restrict__ rowptr, int* __restrict__ cursor,
    int* __restrict__ ssrc, int* __restrict__ sdst, int E)
{
    int e = blockIdx.x * blockDim.x + threadIdx.x;
    if (e >= E) return;
    int d = dst[e];
    int p = rowptr[d] + atomicAdd(&cursor[d], 1);
    ssrc[p] = src[e];
    sdst[p] = d;
}

// ---------------- precision-split converts ----------------

__global__ __launch_bounds__(256) void convert_x(
    const float* __restrict__ x, ushort* __restrict__ Xh, ushort* __restrict__ Xl,
    long total4)
{
    long i = (long)blockIdx.x * blockDim.x + threadIdx.x;
    long stride = (long)gridDim.x * blockDim.x;
    for (; i < total4; i += stride) {
        float4 v = *(const float4*)(x + i * 4);
        ushort4 h, lo;
        h.x = f2bf(v.x); lo.x = f2bf(v.x - bf2f(h.x));
        h.y = f2bf(v.y); lo.y = f2bf(v.y - bf2f(h.y));
        h.z = f2bf(v.z); lo.z = f2bf(v.z - bf2f(h.z));
        h.w = f2bf(v.w); lo.w = f2bf(v.w - bf2f(h.w));
        *(ushort4*)(Xh + i * 4) = h;
        *(ushort4*)(Xl + i * 4) = lo;
    }
}

__global__ __launch_bounds__(256) void convert_w(
    const float* __restrict__ W, ushort* __restrict__ Wth, ushort* __restrict__ Wtl,
    int K, int M, int Mp)
{
    int idx = blockIdx.x * blockDim.x + threadIdx.x;
    if (idx >= Mp * K) return;
    int c = idx / K, k = idx - c * K;
    float v = (c < M) ? W[(size_t)k * M + c] : 0.f;
    ushort h = f2bf(v);
    Wth[idx] = h;
    Wtl[idx] = f2bf(v - bf2f(h));
}

// ---------------- bf16x3 MFMA GEMM + score epilogue ----------------

#define LDK 40

__global__ __launch_bounds__(256) void gemm_feat(
    const ushort* __restrict__ Ah, const ushort* __restrict__ Al,
    const ushort* __restrict__ Wh, const ushort* __restrict__ Wl,
    const float* __restrict__ alw, const float* __restrict__ arw,
    float* __restrict__ feat, float* __restrict__ el, float* __restrict__ er,
    int N, int K, int M, int H, int D, int ldF)
{
    __shared__ ushort As_h[128 * LDK];
    __shared__ ushort As_l[128 * LDK];
    __shared__ ushort Bs_h[128 * LDK];
    __shared__ ushort Bs_l[128 * LDK];

    const int m0 = blockIdx.x * 128;
    const int n0 = blockIdx.y * 128;
    const int t = threadIdx.x;
    const int w = t >> 6, lane = t & 63;
    const int lr = lane & 15, lg = lane >> 4;
    const int wr = (w >> 1) * 64, wc = (w & 1) * 64;

    f32x4 acc[4][4] = {};

    for (int k0 = 0; k0 < K; k0 += 32) {
        #pragma unroll
        for (int l = 0; l < 2; ++l) {
            int idx = t + l * 256;
            int row = idx >> 2, kk = (idx & 3) * 8;
            bf16x8 vh = {}, vl = {};
            int gr = m0 + row;
            if (gr < N) {
                vh = *(const bf16x8*)(Ah + (size_t)gr * K + k0 + kk);
                vl = *(const bf16x8*)(Al + (size_t)gr * K + k0 + kk);
            }
            bf16x8 wh = *(const bf16x8*)(Wh + (size_t)(n0 + row) * K + k0 + kk);
            bf16x8 wl = *(const bf16x8*)(Wl + (size_t)(n0 + row) * K + k0 + kk);
            *(bf16x8*)&As_h[row * LDK + kk] = vh;
            *(bf16x8*)&As_l[row * LDK + kk] = vl;
            *(bf16x8*)&Bs_h[row * LDK + kk] = wh;
            *(bf16x8*)&Bs_l[row * LDK + kk] = wl;
        }
        __syncthreads();

        bf16x8 a_h[4], a_l[4];
        #pragma unroll
        for (int fi = 0; fi < 4; ++fi) {
            a_h[fi] = *(const bf16x8*)&As_h[(wr + fi * 16 + lr) * LDK + lg * 8];
            a_l[fi] = *(const bf16x8*)&As_l[(wr + fi * 16 + lr) * LDK + lg * 8];
        }
        #pragma unroll
        for (int fj = 0; fj < 4; ++fj) {
            bf16x8 b_h = *(const bf16x8*)&Bs_h[(wc + fj * 16 + lr) * LDK + lg * 8];
            bf16x8 b_l = *(const bf16x8*)&Bs_l[(wc + fj * 16 + lr) * LDK + lg * 8];
            #pragma unroll
            for (int fi = 0; fi < 4; ++fi) {
                acc[fi][fj] = __builtin_amdgcn_mfma_f32_16x16x32_bf16(a_h[fi], b_h, acc[fi][fj], 0, 0, 0);
                acc[fi][fj] = __builtin_amdgcn_mfma_f32_16x16x32_bf16(a_l[fi], b_h, acc[fi][fj], 0, 0, 0);
                acc[fi][fj] = __builtin_amdgcn_mfma_f32_16x16x32_bf16(a_h[fi], b_l, acc[fi][fj], 0, 0, 0);
            }
        }
        __syncthreads();
    }

    #pragma unroll
    for (int fi = 0; fi < 4; ++fi) {
        #pragma unroll
        for (int q = 0; q < 4; ++q) {
            int row = m0 + wr + fi * 16 + 4 * lg + q;
            if (row < N) {
                #pragma unroll
                for (int fj = 0; fj < 4; ++fj) {
                    int col = n0 + wc + fj * 16 + lr;
                    if (col < M) feat[(size_t)row * ldF + col] = acc[fi][fj][q];
                }
            }
        }
    }

    const int head = (n0 + wc) / D;
    if (head < H) {
        float alv[4], arv[4];
        #pragma unroll
        for (int fj = 0; fj < 4; ++fj) {
            int col = n0 + wc + fj * 16 + lr;
            alv[fj] = (col < M) ? alw[col] : 0.f;
            arv[fj] = (col < M) ? arw[col] : 0.f;
        }
        #pragma unroll
        for (int fi = 0; fi < 4; ++fi) {
            #pragma unroll
            for (int q = 0; q < 4; ++q) {
                float s1 = 0.f, s2 = 0.f;
                #pragma unroll
                for (int fj = 0; fj < 4; ++fj) {
                    s1 = fmaf(acc[fi][fj][q], alv[fj], s1);
                    s2 = fmaf(acc[fi][fj][q], arv[fj], s2);
                }
                #pragma unroll
                for (int mask = 1; mask <= 8; mask <<= 1) {
                    s1 += __shfl_xor(s1, mask);
                    s2 += __shfl_xor(s2, mask);
                }
                int row = m0 + wr + fi * 16 + 4 * lg + q;
                if (lr == 0 && row < N) {
                    el[(size_t)row * H + head] = s1;
                    er[(size_t)row * H + head] = s2;
                }
            }
        }
    }
}

// ---------------- edge scores in CSR order ----------------

__global__ __launch_bounds__(256) void edge_score4(
    const int* __restrict__ ssrc, const int* __restrict__ sdst,
    const float* __restrict__ el, const float* __restrict__ er,
    float* __restrict__ sc, int E)
{
    int p = blockIdx.x * blockDim.x + threadIdx.x;
    if (p >= E) return;
    int s = ssrc[p], d = sdst[p];
    float4 a = *(const float4*)(el + (size_t)s * 4);
    float4 b = *(const float4*)(er + (size_t)d * 4);
    float4 v;
    v.x = a.x + b.x; v.x = v.x > 0.f ? v.x : 0.2f * v.x;
    v.y = a.y + b.y; v.y = v.y > 0.f ? v.y : 0.2f * v.y;
    v.z = a.z + b.z; v.z = v.z > 0.f ? v.z : 0.2f * v.z;
    v.w = a.w + b.w; v.w = v.w > 0.f ? v.w : 0.2f * v.w;
    *(float4*)(sc + (size_t)p * 4) = v;
}

__global__ __launch_bounds__(256) void edge_score1(
    const int* __restrict__ ssrc, const int* __restrict__ sdst,
    const float* __restrict__ el, const float* __restrict__ er,
    float* __restrict__ sc, int E)
{
    int p = blockIdx.x * blockDim.x + threadIdx.x;
    if (p >= E) return;
    float v = el[ssrc[p]] + er[sdst[p]];
    sc[p] = v > 0.f ? v : 0.2f * v;
}

// ---------------- fused softmax aggregation ----------------

// one wave per node; lane -> float4 of channels, h = lane>>4, sub = lane&15.
// pass1: lane-parallel max+denom over sc (linear), shfl-reduced in 16-lane groups.
// pass2: serial feat gather (float4/lane), weight recomputed from sc.
__global__ __launch_bounds__(256) void node_aggr256(
    const int* __restrict__ rowptr, const int* __restrict__ ssrc,
    const float* __restrict__ sc, const float* __restrict__ feat,
    const float* __restrict__ bias,
    ushort* __restrict__ Ah_out, ushort* __restrict__ Al_out, int N)
{
    int n = blockIdx.x * 4 + (threadIdx.x >> 6);
    if (n >= N) return;
    int lane = threadIdx.x & 63;
    int h = lane >> 4, sub = lane & 15;
    int beg = rowptr[n], end = rowptr[n + 1];

    float m = -__builtin_inff();
    for (int j = beg + sub; j < end; j += 16)
        m = fmaxf(m, sc[(size_t)j * 4 + h]);
    #pragma unroll
    for (int mask = 1; mask <= 8; mask <<= 1)
        m = fmaxf(m, __shfl_xor(m, mask));

    float denom = 0.f;
    for (int j = beg + sub; j < end; j += 16)
        denom += __expf(sc[(size_t)j * 4 + h] - m);
    #pragma unroll
    for (int mask = 1; mask <= 8; mask <<= 1)
        denom += __shfl_xor(denom, mask);

    float inv = 1.f / fmaxf(denom, 1e-9f);
    float ax = 0.f, ay = 0.f, az = 0.f, aw = 0.f;
    for (int j = beg; j < end; ++j) {
        float wgt = __expf(sc[(size_t)j * 4 + h] - m);
        int s = ssrc[j];
        float4 f = *(const float4*)(feat + (size_t)s * 256 + lane * 4);
        ax = fmaf(wgt, f.x, ax);
        ay = fmaf(wgt, f.y, ay);
        az = fmaf(wgt, f.z, az);
        aw = fmaf(wgt, f.w, aw);
    }
    float v0 = fmaf(ax, inv, bias[lane * 4 + 0]);
    float v1 = fmaf(ay, inv, bias[lane * 4 + 1]);
    float v2 = fmaf(az, inv, bias[lane * 4 + 2]);
    float v3 = fmaf(aw, inv, bias[lane * 4 + 3]);
    ushort4 hh, lo;
    hh.x = f2bf(v0); lo.x = f2bf(v0 - bf2f(hh.x));
    hh.y = f2bf(v1); lo.y = f2bf(v1 - bf2f(hh.y));
    hh.z = f2bf(v2); lo.z = f2bf(v2 - bf2f(hh.z));
    hh.w = f2bf(v3); lo.w = f2bf(v3 - bf2f(hh.w));
    *(ushort4*)(Ah_out + (size_t)n * 256 + lane * 4) = hh;
    *(ushort4*)(Al_out + (size_t)n * 256 + lane * 4) = lo;
}

// wave per node; H=1, D=47, feat stride 48
__global__ __launch_bounds__(256) void node_aggr47(
    const int* __restrict__ rowptr, const int* __restrict__ ssrc,
    const float* __restrict__ sc, const float* __restrict__ feat,
    const float* __restrict__ bias, float* __restrict__ out, int N)
{
    int n = blockIdx.x * 4 + (threadIdx.x >> 6);
    if (n >= N) return;
    int lane = threadIdx.x & 63;
    int beg = rowptr[n], end = rowptr[n + 1];

    float m = -__builtin_inff();
    for (int j = beg + lane; j < end; j += 64)
        m = fmaxf(m, sc[j]);
    #pragma unroll
    for (int mask = 1; mask <= 32; mask <<= 1)
        m = fmaxf(m, __shfl_xor(m, mask));

    float denom = 0.f;
    for (int j = beg + lane; j < end; j += 64)
        denom += __expf(sc[j] - m);
    #pragma unroll
    for (int mask = 1; mask <= 32; mask <<= 1)
        denom += __shfl_xor(denom, mask);

    float inv = 1.f / fmaxf(denom, 1e-9f);
    float acc = 0.f;
    for (int j = beg; j < end; ++j) {
        float wgt = __expf(sc[j] - m);
        int s = ssrc[j];
        float f = (lane < 47) ? feat[(size_t)s * 48 + lane] : 0.f;
        acc = fmaf(wgt, f, acc);
    }
    if (lane < 47)
        out[(size_t)n * 47 + lane] = fmaf(acc, inv, bias[lane]);
}

// ---------------- launch ----------------

extern "C" void kernel_launch(void* const* d_in, const int* in_sizes, int n_in,
                              void* d_out, int out_size, void* d_ws, size_t ws_size,
                              hipStream_t stream) {
    const float* x   = (const float*)d_in[0];
    const int*   src = (const int*)d_in[1];
    const int*   dst = (const int*)d_in[2];
    const float* W1  = (const float*)d_in[3];
    const float* al1 = (const float*)d_in[4];
    const float* ar1 = (const float*)d_in[5];
    const float* b1  = (const float*)d_in[6];
    const float* W2  = (const float*)d_in[7];
    const float* al2 = (const float*)d_in[8];
    const float* ar2 = (const float*)d_in[9];
    const float* b2  = (const float*)d_in[10];
    const float* W3  = (const float*)d_in[11];
    const float* al3 = (const float*)d_in[12];
    const float* ar3 = (const float*)d_in[13];
    const float* b3  = (const float*)d_in[14];
    float* out = (float*)d_out;

    const int N = GAT_N, E = GAT_E;
    const int chunk = (N + SCAN_B - 1) / SCAN_B;

    char* wsb = (char*)d_ws;
    size_t o = 0;
    float*  feat  = (float*)(wsb + o);  o += (size_t)N * 256 * 4;
    ushort* Ah    = (ushort*)(wsb + o); o += (size_t)N * 256 * 2;
    ushort* Al    = (ushort*)(wsb + o); o += (size_t)N * 256 * 2;
    float*  el    = (float*)(wsb + o);  o += (size_t)N * 4 * 4;
    float*  er    = (float*)(wsb + o);  o += (size_t)N * 4 * 4;
    int* rowptr   = (int*)(wsb + o);    o += (size_t)(N + 1) * 4;
    int* cnt      = (int*)(wsb + o);    o += (size_t)N * 4;
    int* cursor   = (int*)(wsb + o);    o += (size_t)N * 4;
    int* ssrc     = (int*)(wsb + o);    o += (size_t)E * 4;
    int* sdst     = (int*)(wsb + o);    o += (size_t)E * 4;
    float* scbuf  = (float*)(wsb + o);  o += (size_t)E * 4 * 4;
    int* partials = (int*)(wsb + o);    o += (size_t)SCAN_B * 4;
    ushort* Wt1h  = (ushort*)(wsb + o); o += (size_t)256 * 128 * 2;
    ushort* Wt1l  = (ushort*)(wsb + o); o += (size_t)256 * 128 * 2;
    ushort* Wt2h  = (ushort*)(wsb + o); o += (size_t)256 * 256 * 2;
    ushort* Wt2l  = (ushort*)(wsb + o); o += (size_t)256 * 256 * 2;
    ushort* Wt3h  = (ushort*)(wsb + o); o += (size_t)128 * 256 * 2;
    ushort* Wt3l  = (ushort*)(wsb + o); o += (size_t)128 * 256 * 2;
    ushort* Xh = Ah;
    ushort* Xl = Al;

    dim3 blk(256);
    int gE = (E + 255) / 256;
    int gN = (N + 3) / 4;
    dim3 gemmG((N + 127) / 128, 2);
    dim3 gemmG3((N + 127) / 128, 1);

    // ---- CSR build
    zero_ints<<<64, blk, 0, stream>>>(cnt, 2 * N);
    count_k<<<gE, blk, 0, stream>>>(dst, cnt, E);
    csr_partial<<<SCAN_B, blk, 0, stream>>>(cnt, partials, N, chunk);
    csr_scanp<<<1, SCAN_B, 0, stream>>>(partials, rowptr, N);
    csr_write<<<SCAN_B, blk, 0, stream>>>(cnt, partials, rowptr, N, chunk);
    scatter_k<<<gE, blk, 0, stream>>>(src, dst, rowptr, cursor, ssrc, sdst, E);

    // ---- converts
    convert_x<<<2048, blk, 0, stream>>>(x, Xh, Xl, (long)N * 128 / 4);
    convert_w<<<(256 * 128 + 255) / 256, blk, 0, stream>>>(W1, Wt1h, Wt1l, 128, 256, 256);
    convert_w<<<(256 * 256 + 255) / 256, blk, 0, stream>>>(W2, Wt2h, Wt2l, 256, 256, 256);
    convert_w<<<(128 * 256 + 255) / 256, blk, 0, stream>>>(W3, Wt3h, Wt3l, 256, 47, 128);

    // ---- layer 1
    gemm_feat<<<gemmG, blk, 0, stream>>>(Xh, Xl, Wt1h, Wt1l, al1, ar1,
                                         feat, el, er, N, 128, 256, 4, 64, 256);
    edge_score4<<<gE, blk, 0, stream>>>(ssrc, sdst, el, er, scbuf, E);
    node_aggr256<<<gN, blk, 0, stream>>>(rowptr, ssrc, scbuf, feat, b1, Ah, Al, N);

    // ---- layer 2
    gemm_feat<<<gemmG, blk, 0, stream>>>(Ah, Al, Wt2h, Wt2l, al2, ar2,
                                         feat, el, er, N, 256, 256, 4, 64, 256);
    edge_score4<<<gE, blk, 0, stream>>>(ssrc, sdst, el, er, scbuf, E);
    node_aggr256<<<gN, blk, 0, stream>>>(rowptr, ssrc, scbuf, feat, b2, Ah, Al, N);

    // ---- layer 3 (feat stride 48)
    gemm_feat<<<gemmG3, blk, 0, stream>>>(Ah, Al, Wt3h, Wt3l, al3, ar3,
                                          feat, el, er, N, 256, 47, 1, 47, 48);
    edge_score1<<<gE, blk, 0, stream>>>(ssrc, sdst, el, er, scbuf, E);
    node_aggr47<<<gN, blk, 0, stream>>>(rowptr, ssrc, scbuf, feat, b3, out, N);
}

// Round 7
// 311.547 us; speedup vs baseline: 1.2978x; 1.0664x over previous
//
#include <hip/hip_runtime.h>
#include <cstddef>

#define GAT_N 50000
#define GAT_E 300000
#define SCAN_B 256

typedef short bf16x8 __attribute__((ext_vector_type(8)));
typedef float f32x4  __attribute__((ext_vector_type(4)));

__device__ __forceinline__ ushort f2bf(float f) {
    unsigned u = __float_as_uint(f);
    return (ushort)((u + 0x7fffu + ((u >> 16) & 1u)) >> 16);
}
__device__ __forceinline__ float bf2f(ushort h) {
    return __uint_as_float((unsigned)h << 16);
}

// ---------------- CSR build ----------------

__global__ __launch_bounds__(256) void zero_ints(int* __restrict__ a, int n) {
    int i = blockIdx.x * blockDim.x + threadIdx.x;
    int stride = gridDim.x * blockDim.x;
    for (; i < n; i += stride) a[i] = 0;
}

__global__ __launch_bounds__(256) void count_k(
    const int* __restrict__ dst, int* __restrict__ cnt, int E)
{
    int e = blockIdx.x * blockDim.x + threadIdx.x;
    if (e < E) atomicAdd(&cnt[dst[e]], 1);
}

__global__ __launch_bounds__(256) void csr_partial(
    const int* __restrict__ cnt, int* __restrict__ partials, int N, int chunk)
{
    __shared__ int red[256];
    int b = blockIdx.x, t = threadIdx.x;
    int s = 0;
    for (int i = t; i < chunk; i += 256) {
        int idx = b * chunk + i;
        if (idx < N) s += cnt[idx];
    }
    red[t] = s;
    __syncthreads();
    for (int off = 128; off > 0; off >>= 1) {
        if (t < off) red[t] += red[t + off];
        __syncthreads();
    }
    if (t == 0) partials[b] = red[0];
}

__global__ __launch_bounds__(SCAN_B) void csr_scanp(
    int* __restrict__ partials, int* __restrict__ rowptr, int N)
{
    __shared__ int sc[SCAN_B];
    int t = threadIdx.x;
    int v = partials[t];
    sc[t] = v;
    __syncthreads();
    for (int off = 1; off < SCAN_B; off <<= 1) {
        int u = (t >= off) ? sc[t - off] : 0;
        __syncthreads();
        sc[t] += u;
        __syncthreads();
    }
    partials[t] = sc[t] - v;
    if (t == SCAN_B - 1) rowptr[N] = sc[t];
}

__global__ __launch_bounds__(256) void csr_write(
    const int* __restrict__ cnt, const int* __restrict__ partials,
    int* __restrict__ rowptr, int N, int chunk)
{
    __shared__ int sc[256];
    int b = blockIdx.x, t = threadIdx.x;
    int idx = b * chunk + t;
    int v = (t < chunk && idx < N) ? cnt[idx] : 0;
    sc[t] = v;
    __syncthreads();
    for (int off = 1; off < 256; off <<= 1) {
        int u = (t >= off) ? sc[t - off] : 0;
        __syncthreads();
        sc[t] += u;
        __syncthreads();
    }
    if (t < chunk && idx < N) rowptr[idx] = partials[b] + sc[t] - v;
}

__global__ __launch_bounds__(256) void scatter_k(
    const int* __restrict__ src, const int* __restrict__ dst,
    const int* __restrict__ rowptr, int* __restrict__ cursor,
    int* __restrict__ ssrc, int* __restrict__ sdst, int E)
{
    int e = blockIdx.x * blockDim.x + threadIdx.x;
    if (e >= E) return;
    int d = dst[e];
    int p = rowptr[d] + atomicAdd(&cursor[d], 1);
    ssrc[p] = src[e];
    sdst[p] = d;
}

// ---------------- precision-split converts ----------------

__global__ __launch_bounds__(256) void convert_x(
    const float* __restrict__ x, ushort* __restrict__ Xh, ushort* __restrict__ Xl,
    long total4)
{
    long i = (long)blockIdx.x * blockDim.x + threadIdx.x;
    long stride = (long)gridDim.x * blockDim.x;
    for (; i < total4; i += stride) {
        float4 v = *(const float4*)(x + i * 4);
        ushort4 h, lo;
        h.x = f2bf(v.x); lo.x = f2bf(v.x - bf2f(h.x));
        h.y = f2bf(v.y); lo.y = f2bf(v.y - bf2f(h.y));
        h.z = f2bf(v.z); lo.z = f2bf(v.z - bf2f(h.z));
        h.w = f2bf(v.w); lo.w = f2bf(v.w - bf2f(h.w));
        *(ushort4*)(Xh + i * 4) = h;
        *(ushort4*)(Xl + i * 4) = lo;
    }
}

__global__ __launch_bounds__(256) void convert_w(
    const float* __restrict__ W, ushort* __restrict__ Wth, ushort* __restrict__ Wtl,
    int K, int M, int Mp)
{
    int idx = blockIdx.x * blockDim.x + threadIdx.x;
    if (idx >= Mp * K) return;
    int c = idx / K, k = idx - c * K;
    float v = (c < M) ? W[(size_t)k * M + c] : 0.f;
    ushort h = f2bf(v);
    Wth[idx] = h;
    Wtl[idx] = f2bf(v - bf2f(h));
}

// ---------------- bf16x3 MFMA GEMM + score epilogue ----------------
// 64x128 tile, BK=32, 4 waves (2 row x 2 col), wave = 32 rows x 64 cols.

#define LDK 40

__global__ __launch_bounds__(256) void gemm_feat(
    const ushort* __restrict__ Ah, const ushort* __restrict__ Al,
    const ushort* __restrict__ Wh, const ushort* __restrict__ Wl,
    const float* __restrict__ alw, const float* __restrict__ arw,
    float* __restrict__ feat, float* __restrict__ el, float* __restrict__ er,
    int N, int K, int M, int H, int D, int ldF)
{
    __shared__ ushort As_h[64 * LDK];
    __shared__ ushort As_l[64 * LDK];
    __shared__ ushort Bs_h[128 * LDK];
    __shared__ ushort Bs_l[128 * LDK];

    const int m0 = blockIdx.x * 64;
    const int n0 = blockIdx.y * 128;
    const int t = threadIdx.x;
    const int w = t >> 6, lane = t & 63;
    const int lr = lane & 15, lg = lane >> 4;
    const int wr = (w >> 1) * 32, wc = (w & 1) * 64;

    f32x4 acc[2][4] = {};

    for (int k0 = 0; k0 < K; k0 += 32) {
        // A: 64 rows x 32 k = 256 chunks of bf16x8, one per thread
        {
            int row = t >> 2, kk = (t & 3) * 8;
            bf16x8 vh = {}, vl = {};
            int gr = m0 + row;
            if (gr < N) {
                vh = *(const bf16x8*)(Ah + (size_t)gr * K + k0 + kk);
                vl = *(const bf16x8*)(Al + (size_t)gr * K + k0 + kk);
            }
            *(bf16x8*)&As_h[row * LDK + kk] = vh;
            *(bf16x8*)&As_l[row * LDK + kk] = vl;
        }
        // B: 128 rows x 32 k = 512 chunks, two per thread
        #pragma unroll
        for (int l = 0; l < 2; ++l) {
            int idx = t + l * 256;
            int row = idx >> 2, kk = (idx & 3) * 8;
            *(bf16x8*)&Bs_h[row * LDK + kk] = *(const bf16x8*)(Wh + (size_t)(n0 + row) * K + k0 + kk);
            *(bf16x8*)&Bs_l[row * LDK + kk] = *(const bf16x8*)(Wl + (size_t)(n0 + row) * K + k0 + kk);
        }
        __syncthreads();

        bf16x8 a_h[2], a_l[2];
        #pragma unroll
        for (int fi = 0; fi < 2; ++fi) {
            a_h[fi] = *(const bf16x8*)&As_h[(wr + fi * 16 + lr) * LDK + lg * 8];
            a_l[fi] = *(const bf16x8*)&As_l[(wr + fi * 16 + lr) * LDK + lg * 8];
        }
        #pragma unroll
        for (int fj = 0; fj < 4; ++fj) {
            bf16x8 b_h = *(const bf16x8*)&Bs_h[(wc + fj * 16 + lr) * LDK + lg * 8];
            bf16x8 b_l = *(const bf16x8*)&Bs_l[(wc + fj * 16 + lr) * LDK + lg * 8];
            #pragma unroll
            for (int fi = 0; fi < 2; ++fi) {
                acc[fi][fj] = __builtin_amdgcn_mfma_f32_16x16x32_bf16(a_h[fi], b_h, acc[fi][fj], 0, 0, 0);
                acc[fi][fj] = __builtin_amdgcn_mfma_f32_16x16x32_bf16(a_l[fi], b_h, acc[fi][fj], 0, 0, 0);
                acc[fi][fj] = __builtin_amdgcn_mfma_f32_16x16x32_bf16(a_h[fi], b_l, acc[fi][fj], 0, 0, 0);
            }
        }
        __syncthreads();
    }

    // C/D: row = 4*lg + q, col = lr within each 16x16 frag
    #pragma unroll
    for (int fi = 0; fi < 2; ++fi) {
        #pragma unroll
        for (int q = 0; q < 4; ++q) {
            int row = m0 + wr + fi * 16 + 4 * lg + q;
            if (row < N) {
                #pragma unroll
                for (int fj = 0; fj < 4; ++fj) {
                    int col = n0 + wc + fj * 16 + lr;
                    if (col < M) feat[(size_t)row * ldF + col] = acc[fi][fj][q];
                }
            }
        }
    }

    const int head = (n0 + wc) / D;
    if (head < H) {
        float alv[4], arv[4];
        #pragma unroll
        for (int fj = 0; fj < 4; ++fj) {
            int col = n0 + wc + fj * 16 + lr;
            alv[fj] = (col < M) ? alw[col] : 0.f;
            arv[fj] = (col < M) ? arw[col] : 0.f;
        }
        #pragma unroll
        for (int fi = 0; fi < 2; ++fi) {
            #pragma unroll
            for (int q = 0; q < 4; ++q) {
                float s1 = 0.f, s2 = 0.f;
                #pragma unroll
                for (int fj = 0; fj < 4; ++fj) {
                    s1 = fmaf(acc[fi][fj][q], alv[fj], s1);
                    s2 = fmaf(acc[fi][fj][q], arv[fj], s2);
                }
                #pragma unroll
                for (int mask = 1; mask <= 8; mask <<= 1) {
                    s1 += __shfl_xor(s1, mask);
                    s2 += __shfl_xor(s2, mask);
                }
                int row = m0 + wr + fi * 16 + 4 * lg + q;
                if (lr == 0 && row < N) {
                    el[(size_t)row * H + head] = s1;
                    er[(size_t)row * H + head] = s2;
                }
            }
        }
    }
}

// ---------------- edge scores in CSR order ----------------

__global__ __launch_bounds__(256) void edge_score4(
    const int* __restrict__ ssrc, const int* __restrict__ sdst,
    const float* __restrict__ el, const float* __restrict__ er,
    float* __restrict__ sc, int E)
{
    int p = blockIdx.x * blockDim.x + threadIdx.x;
    if (p >= E) return;
    int s = ssrc[p], d = sdst[p];
    float4 a = *(const float4*)(el + (size_t)s * 4);
    float4 b = *(const float4*)(er + (size_t)d * 4);
    float4 v;
    v.x = a.x + b.x; v.x = v.x > 0.f ? v.x : 0.2f * v.x;
    v.y = a.y + b.y; v.y = v.y > 0.f ? v.y : 0.2f * v.y;
    v.z = a.z + b.z; v.z = v.z > 0.f ? v.z : 0.2f * v.z;
    v.w = a.w + b.w; v.w = v.w > 0.f ? v.w : 0.2f * v.w;
    *(float4*)(sc + (size_t)p * 4) = v;
}

__global__ __launch_bounds__(256) void edge_score1(
    const int* __restrict__ ssrc, const int* __restrict__ sdst,
    const float* __restrict__ el, const float* __restrict__ er,
    float* __restrict__ sc, int E)
{
    int p = blockIdx.x * blockDim.x + threadIdx.x;
    if (p >= E) return;
    float v = el[ssrc[p]] + er[sdst[p]];
    sc[p] = v > 0.f ? v : 0.2f * v;
}

// ---------------- fused softmax aggregation ----------------

// one wave per node; lane -> float4 of channels, h = lane>>4, sub = lane&15.
// gather loop unrolled x4 for memory-level parallelism.
__global__ __launch_bounds__(256) void node_aggr256(
    const int* __restrict__ rowptr, const int* __restrict__ ssrc,
    const float* __restrict__ sc, const float* __restrict__ feat,
    const float* __restrict__ bias,
    ushort* __restrict__ Ah_out, ushort* __restrict__ Al_out, int N)
{
    int n = blockIdx.x * 4 + (threadIdx.x >> 6);
    if (n >= N) return;
    int lane = threadIdx.x & 63;
    int h = lane >> 4, sub = lane & 15;
    int beg = rowptr[n], end = rowptr[n + 1];

    float m = -__builtin_inff();
    for (int j = beg + sub; j < end; j += 16)
        m = fmaxf(m, sc[(size_t)j * 4 + h]);
    #pragma unroll
    for (int mask = 1; mask <= 8; mask <<= 1)
        m = fmaxf(m, __shfl_xor(m, mask));

    float denom = 0.f;
    for (int j = beg + sub; j < end; j += 16)
        denom += __expf(sc[(size_t)j * 4 + h] - m);
    #pragma unroll
    for (int mask = 1; mask <= 8; mask <<= 1)
        denom += __shfl_xor(denom, mask);

    float inv = 1.f / fmaxf(denom, 1e-9f);
    float ax = 0.f, ay = 0.f, az = 0.f, aw = 0.f;
    int j = beg;
    for (; j + 4 <= end; j += 4) {
        int s0 = ssrc[j + 0], s1 = ssrc[j + 1], s2 = ssrc[j + 2], s3 = ssrc[j + 3];
        float w0 = __expf(sc[(size_t)(j + 0) * 4 + h] - m);
        float w1 = __expf(sc[(size_t)(j + 1) * 4 + h] - m);
        float w2 = __expf(sc[(size_t)(j + 2) * 4 + h] - m);
        float w3 = __expf(sc[(size_t)(j + 3) * 4 + h] - m);
        float4 f0 = *(const float4*)(feat + (size_t)s0 * 256 + lane * 4);
        float4 f1 = *(const float4*)(feat + (size_t)s1 * 256 + lane * 4);
        float4 f2 = *(const float4*)(feat + (size_t)s2 * 256 + lane * 4);
        float4 f3 = *(const float4*)(feat + (size_t)s3 * 256 + lane * 4);
        ax = fmaf(w0, f0.x, fmaf(w1, f1.x, fmaf(w2, f2.x, fmaf(w3, f3.x, ax))));
        ay = fmaf(w0, f0.y, fmaf(w1, f1.y, fmaf(w2, f2.y, fmaf(w3, f3.y, ay))));
        az = fmaf(w0, f0.z, fmaf(w1, f1.z, fmaf(w2, f2.z, fmaf(w3, f3.z, az))));
        aw = fmaf(w0, f0.w, fmaf(w1, f1.w, fmaf(w2, f2.w, fmaf(w3, f3.w, aw))));
    }
    for (; j < end; ++j) {
        float wgt = __expf(sc[(size_t)j * 4 + h] - m);
        int s = ssrc[j];
        float4 f = *(const float4*)(feat + (size_t)s * 256 + lane * 4);
        ax = fmaf(wgt, f.x, ax);
        ay = fmaf(wgt, f.y, ay);
        az = fmaf(wgt, f.z, az);
        aw = fmaf(wgt, f.w, aw);
    }
    float v0 = fmaf(ax, inv, bias[lane * 4 + 0]);
    float v1 = fmaf(ay, inv, bias[lane * 4 + 1]);
    float v2 = fmaf(az, inv, bias[lane * 4 + 2]);
    float v3 = fmaf(aw, inv, bias[lane * 4 + 3]);
    ushort4 hh, lo;
    hh.x = f2bf(v0); lo.x = f2bf(v0 - bf2f(hh.x));
    hh.y = f2bf(v1); lo.y = f2bf(v1 - bf2f(hh.y));
    hh.z = f2bf(v2); lo.z = f2bf(v2 - bf2f(hh.z));
    hh.w = f2bf(v3); lo.w = f2bf(v3 - bf2f(hh.w));
    *(ushort4*)(Ah_out + (size_t)n * 256 + lane * 4) = hh;
    *(ushort4*)(Al_out + (size_t)n * 256 + lane * 4) = lo;
}

// wave per node; H=1, D=47, feat stride 48
__global__ __launch_bounds__(256) void node_aggr47(
    const int* __restrict__ rowptr, const int* __restrict__ ssrc,
    const float* __restrict__ sc, const float* __restrict__ feat,
    const float* __restrict__ bias, float* __restrict__ out, int N)
{
    int n = blockIdx.x * 4 + (threadIdx.x >> 6);
    if (n >= N) return;
    int lane = threadIdx.x & 63;
    int beg = rowptr[n], end = rowptr[n + 1];

    float m = -__builtin_inff();
    for (int j = beg + lane; j < end; j += 64)
        m = fmaxf(m, sc[j]);
    #pragma unroll
    for (int mask = 1; mask <= 32; mask <<= 1)
        m = fmaxf(m, __shfl_xor(m, mask));

    float denom = 0.f;
    for (int j = beg + lane; j < end; j += 64)
        denom += __expf(sc[j] - m);
    #pragma unroll
    for (int mask = 1; mask <= 32; mask <<= 1)
        denom += __shfl_xor(denom, mask);

    float inv = 1.f / fmaxf(denom, 1e-9f);
    float acc = 0.f;
    int j = beg;
    for (; j + 4 <= end; j += 4) {
        int s0 = ssrc[j + 0], s1 = ssrc[j + 1], s2 = ssrc[j + 2], s3 = ssrc[j + 3];
        float w0 = __expf(sc[j + 0] - m);
        float w1 = __expf(sc[j + 1] - m);
        float w2 = __expf(sc[j + 2] - m);
        float w3 = __expf(sc[j + 3] - m);
        float f0 = (lane < 47) ? feat[(size_t)s0 * 48 + lane] : 0.f;
        float f1 = (lane < 47) ? feat[(size_t)s1 * 48 + lane] : 0.f;
        float f2 = (lane < 47) ? feat[(size_t)s2 * 48 + lane] : 0.f;
        float f3 = (lane < 47) ? feat[(size_t)s3 * 48 + lane] : 0.f;
        acc = fmaf(w0, f0, fmaf(w1, f1, fmaf(w2, f2, fmaf(w3, f3, acc))));
    }
    for (; j < end; ++j) {
        float wgt = __expf(sc[j] - m);
        int s = ssrc[j];
        float f = (lane < 47) ? feat[(size_t)s * 48 + lane] : 0.f;
        acc = fmaf(wgt, f, acc);
    }
    if (lane < 47)
        out[(size_t)n * 47 + lane] = fmaf(acc, inv, bias[lane]);
}

// ---------------- launch ----------------

extern "C" void kernel_launch(void* const* d_in, const int* in_sizes, int n_in,
                              void* d_out, int out_size, void* d_ws, size_t ws_size,
                              hipStream_t stream) {
    const float* x   = (const float*)d_in[0];
    const int*   src = (const int*)d_in[1];
    const int*   dst = (const int*)d_in[2];
    const float* W1  = (const float*)d_in[3];
    const float* al1 = (const float*)d_in[4];
    const float* ar1 = (const float*)d_in[5];
    const float* b1  = (const float*)d_in[6];
    const float* W2  = (const float*)d_in[7];
    const float* al2 = (const float*)d_in[8];
    const float* ar2 = (const float*)d_in[9];
    const float* b2  = (const float*)d_in[10];
    const float* W3  = (const float*)d_in[11];
    const float* al3 = (const float*)d_in[12];
    const float* ar3 = (const float*)d_in[13];
    const float* b3  = (const float*)d_in[14];
    float* out = (float*)d_out;

    const int N = GAT_N, E = GAT_E;
    const int chunk = (N + SCAN_B - 1) / SCAN_B;

    char* wsb = (char*)d_ws;
    size_t o = 0;
    float*  feat  = (float*)(wsb + o);  o += (size_t)N * 256 * 4;
    ushort* Ah    = (ushort*)(wsb + o); o += (size_t)N * 256 * 2;
    ushort* Al    = (ushort*)(wsb + o); o += (size_t)N * 256 * 2;
    float*  el    = (float*)(wsb + o);  o += (size_t)N * 4 * 4;
    float*  er    = (float*)(wsb + o);  o += (size_t)N * 4 * 4;
    int* rowptr   = (int*)(wsb + o);    o += (size_t)(N + 1) * 4;
    int* cnt      = (int*)(wsb + o);    o += (size_t)N * 4;
    int* cursor   = (int*)(wsb + o);    o += (size_t)N * 4;
    int* ssrc     = (int*)(wsb + o);    o += (size_t)E * 4;
    int* sdst     = (int*)(wsb + o);    o += (size_t)E * 4;
    float* scbuf  = (float*)(wsb + o);  o += (size_t)E * 4 * 4;
    int* partials = (int*)(wsb + o);    o += (size_t)SCAN_B * 4;
    ushort* Wt1h  = (ushort*)(wsb + o); o += (size_t)256 * 128 * 2;
    ushort* Wt1l  = (ushort*)(wsb + o); o += (size_t)256 * 128 * 2;
    ushort* Wt2h  = (ushort*)(wsb + o); o += (size_t)256 * 256 * 2;
    ushort* Wt2l  = (ushort*)(wsb + o); o += (size_t)256 * 256 * 2;
    ushort* Wt3h  = (ushort*)(wsb + o); o += (size_t)128 * 256 * 2;
    ushort* Wt3l  = (ushort*)(wsb + o); o += (size_t)128 * 256 * 2;
    ushort* Xh = Ah;
    ushort* Xl = Al;

    dim3 blk(256);
    int gE = (E + 255) / 256;
    int gN = (N + 3) / 4;
    dim3 gemmG((N + 63) / 64, 2);
    dim3 gemmG3((N + 63) / 64, 1);

    // ---- CSR build
    zero_ints<<<64, blk, 0, stream>>>(cnt, 2 * N);
    count_k<<<gE, blk, 0, stream>>>(dst, cnt, E);
    csr_partial<<<SCAN_B, blk, 0, stream>>>(cnt, partials, N, chunk);
    csr_scanp<<<1, SCAN_B, 0, stream>>>(partials, rowptr, N);
    csr_write<<<SCAN_B, blk, 0, stream>>>(cnt, partials, rowptr, N, chunk);
    scatter_k<<<gE, blk, 0, stream>>>(src, dst, rowptr, cursor, ssrc, sdst, E);

    // ---- converts
    convert_x<<<2048, blk, 0, stream>>>(x, Xh, Xl, (long)N * 128 / 4);
    convert_w<<<(256 * 128 + 255) / 256, blk, 0, stream>>>(W1, Wt1h, Wt1l, 128, 256, 256);
    convert_w<<<(256 * 256 + 255) / 256, blk, 0, stream>>>(W2, Wt2h, Wt2l, 256, 256, 256);
    convert_w<<<(128 * 256 + 255) / 256, blk, 0, stream>>>(W3, Wt3h, Wt3l, 256, 47, 128);

    // ---- layer 1
    gemm_feat<<<gemmG, blk, 0, stream>>>(Xh, Xl, Wt1h, Wt1l, al1, ar1,
                                         feat, el, er, N, 128, 256, 4, 64, 256);
    edge_score4<<<gE, blk, 0, stream>>>(ssrc, sdst, el, er, scbuf, E);
    node_aggr256<<<gN, blk, 0, stream>>>(rowptr, ssrc, scbuf, feat, b1, Ah, Al, N);

    // ---- layer 2
    gemm_feat<<<gemmG, blk, 0, stream>>>(Ah, Al, Wt2h, Wt2l, al2, ar2,
                                         feat, el, er, N, 256, 256, 4, 64, 256);
    edge_score4<<<gE, blk, 0, stream>>>(ssrc, sdst, el, er, scbuf, E);
    node_aggr256<<<gN, blk, 0, stream>>>(rowptr, ssrc, scbuf, feat, b2, Ah, Al, N);

    // ---- layer 3 (feat stride 48)
    gemm_feat<<<gemmG3, blk, 0, stream>>>(Ah, Al, Wt3h, Wt3l, al3, ar3,
                                          feat, el, er, N, 256, 47, 1, 47, 48);
    edge_score1<<<gE, blk, 0, stream>>>(ssrc, sdst, el, er, scbuf, E);
    node_aggr47<<<gN, blk, 0, stream>>>(rowptr, ssrc, scbuf, feat, b3, out, N);
}